// Round 3
// baseline (196.249 us; speedup 1.0000x reference)
//
#include <hip/hip_runtime.h>
#include <cmath>

#define TW 32
#define TH 48
#define HR (TH + 10)     // 58 rows of h-pass results
#define IMG 512
#define SSIM_C1 1e-4f
#define SSIM_C2 9e-4f

struct GaussWin { float g[11]; };

// Bank-decorrelating column swizzle. Bijective on [0,32) for fixed row.
// Row multiplier 5 is odd (coprime to 8), so:
//  - phase-1 b128 stores: 8-lane cycle groups span {0,2,4,6}+5r0 U {0,2,4,6}+5r1,
//    r1=r0+1 -> all 8 bank quads (conflict-free)
//  - phase-1 b32 stores: per cs-block, r in 0..7 -> 5r covers all 8 residues ->
//    full 32-bank permutation
//  - phase-2 reads: per-row bijection, consecutive 8 lanes hit 8 distinct quads
__device__ __forceinline__ int swz(int col, int row) {
    return (col & 24) | ((col + 2 * (col >> 3) + 5 * row) & 7);
}

__launch_bounds__(256, 4)
__global__ void ssim_tile_kernel(const float* __restrict__ x,
                                 const float* __restrict__ y,
                                 const float* __restrict__ conf,
                                 float* __restrict__ partials,
                                 float* __restrict__ out,
                                 int use_ws, float scale,
                                 GaussWin W) {
    __shared__ float4 s_h4[HR * TW];    // 29696 B  (sx, sy, sxx, syy)
    __shared__ float  s_h1[HR * TW];    //  7424 B  (sxy)
    __shared__ float  s_red[4];         // total 37136 B -> 4 blocks/CU

    const int tid = threadIdx.x;
    const int plane = blockIdx.z;              // b*3 + c
    const int tx0 = blockIdx.x * TW;
    const int ty0 = blockIdx.y * TH;
    const int pbase = plane * (IMG * IMG);
    const int cbase = (plane / 3) * (IMG * IMG);

    // ---- Phase 1: horizontal pass, direct from global (no input staging) ----
    // 58 rows x 4 col-groups = 232 strips; one strip per thread, one round,
    // balanced across all 4 waves. Each strip = 8 output cols. Reads 6 aligned
    // float4s per array covering cols [cs-8, cs+16); window indices 3..20 are
    // the 18 taps needed. 16B-aligned reads are fully in- or out-of-bounds,
    // reproducing the reference's zero padding exactly.
    if (tid < HR * 4) {
        int r = tid >> 2;
        int cs = (tid & 3) * 8;
        int gy = ty0 - 5 + r;
        bool rowok = ((unsigned)gy < IMG);
        const float* xrow = x + pbase + gy * IMG;
        const float* yrow = y + pbase + gy * IMG;
        int c0 = tx0 + cs - 8;

        float vx[24], vy[24];
        #pragma unroll
        for (int q = 0; q < 6; q++) {
            int col = c0 + 4 * q;
            float4 fx = make_float4(0.f, 0.f, 0.f, 0.f);
            float4 fy = make_float4(0.f, 0.f, 0.f, 0.f);
            if (rowok && (unsigned)col <= (unsigned)(IMG - 4)) {
                fx = *(const float4*)(xrow + col);
                fy = *(const float4*)(yrow + col);
            }
            vx[4*q+0] = fx.x; vx[4*q+1] = fx.y; vx[4*q+2] = fx.z; vx[4*q+3] = fx.w;
            vy[4*q+0] = fy.x; vy[4*q+1] = fy.y; vy[4*q+2] = fy.z; vy[4*q+3] = fy.w;
        }

        float pxx[18], pyy[18], pxy[18];
        #pragma unroll
        for (int k = 0; k < 18; k++) {
            float a = vx[k + 3], b = vy[k + 3];
            pxx[k] = a * a;
            pyy[k] = b * b;
            pxy[k] = a * b;
        }
        #pragma unroll
        for (int j = 0; j < 8; j++) {
            float sx = 0.f, sy = 0.f, sxx = 0.f, syy = 0.f, sxy = 0.f;
            #pragma unroll
            for (int k = 0; k < 11; k++) {
                float w = W.g[k];
                sx  = fmaf(w, vx[j + k + 3], sx);
                sy  = fmaf(w, vy[j + k + 3], sy);
                sxx = fmaf(w, pxx[j + k], sxx);
                syy = fmaf(w, pyy[j + k], syy);
                sxy = fmaf(w, pxy[j + k], sxy);
            }
            int pc = swz(cs + j, r);
            s_h4[r * TW + pc] = make_float4(sx, sy, sxx, syy);
            s_h1[r * TW + pc] = sxy;
        }
    }
    __syncthreads();

    // ---- Phase 2: vertical pass, 6 vertically-adjacent outputs per thread ----
    const int c  = tid & 31;
    const int r0 = (tid >> 5) * 6;            // 8 groups x 6 rows = 48 rows
    float a0[6], a1[6], a2[6], a3[6], a4[6];
    #pragma unroll
    for (int j = 0; j < 6; j++) { a0[j]=0.f; a1[j]=0.f; a2[j]=0.f; a3[j]=0.f; a4[j]=0.f; }

    #pragma unroll
    for (int t = 0; t < 16; t++) {
        int row = r0 + t;
        int pc = swz(c, row);
        float4 h4 = s_h4[row * TW + pc];
        float  h1 = s_h1[row * TW + pc];
        #pragma unroll
        for (int j = 0; j < 6; j++) {
            int k = t - j;                    // weight index, constant post-unroll
            if (k >= 0 && k <= 10) {
                float w = W.g[k];
                a0[j] = fmaf(w, h4.x, a0[j]);
                a1[j] = fmaf(w, h4.y, a1[j]);
                a2[j] = fmaf(w, h4.z, a2[j]);
                a3[j] = fmaf(w, h4.w, a3[j]);
                a4[j] = fmaf(w, h1,   a4[j]);
            }
        }
    }

    // ---- Epilogue: SSIM + conf weighting + accumulate ----
    float lsum = 0.f;
    #pragma unroll
    for (int j = 0; j < 6; j++) {
        int gy = ty0 + r0 + j, gx = tx0 + c;
        if (gy < IMG) {                        // last y-block has masked rows
            float mu_x = a0[j], mu_y = a1[j];
            float mu_x2 = mu_x * mu_x;
            float mu_y2 = mu_y * mu_y;
            float mu_xy = mu_x * mu_y;
            float sigx  = a2[j] - mu_x2;
            float sigy  = a3[j] - mu_y2;
            float sigxy = a4[j] - mu_xy;
            float num = (2.f * mu_xy + SSIM_C1) * (2.f * sigxy + SSIM_C2);
            float den = (mu_x2 + mu_y2 + SSIM_C1) * (sigx + sigy + SSIM_C2);
            float ssim = num / den;
            float loss = 1.f - ssim;
            loss = fminf(fmaxf(loss, 0.f), 1.f);
            float cf = conf[cbase + gy * IMG + gx];
            lsum = fmaf(loss, cf, lsum);
        }
    }

    // ---- Block reduction ----
    #pragma unroll
    for (int off = 32; off; off >>= 1) lsum += __shfl_down(lsum, off, 64);
    if ((tid & 63) == 0) s_red[tid >> 6] = lsum;
    __syncthreads();
    if (tid == 0) {
        float t = s_red[0] + s_red[1] + s_red[2] + s_red[3];
        if (use_ws) {
            partials[blockIdx.x + gridDim.x * (blockIdx.y + gridDim.y * blockIdx.z)] = t;
        } else {
            atomicAdd(out, t * scale);
        }
    }
}

__global__ void reduce_kernel(const float* __restrict__ partials, int n,
                              float* __restrict__ out, float scale) {
    __shared__ float s_red[4];
    float s = 0.f;
    for (int i = blockIdx.x * 256 + threadIdx.x; i < n; i += gridDim.x * 256)
        s += partials[i];
    #pragma unroll
    for (int off = 32; off; off >>= 1) s += __shfl_down(s, off, 64);
    if ((threadIdx.x & 63) == 0) s_red[threadIdx.x >> 6] = s;
    __syncthreads();
    if (threadIdx.x == 0) {
        float t = (s_red[0] + s_red[1] + s_red[2] + s_red[3]) * scale;
        atomicAdd(out, t);
    }
}

extern "C" void kernel_launch(void* const* d_in, const int* in_sizes, int n_in,
                              void* d_out, int out_size, void* d_ws, size_t ws_size,
                              hipStream_t stream) {
    const float* x    = (const float*)d_in[0];
    const float* y    = (const float*)d_in[1];
    const float* conf = (const float*)d_in[2];
    float* out = (float*)d_out;
    float* partials = (float*)d_ws;

    // Gaussian window, computed like the reference: float64 exp + normalize, cast f32
    GaussWin W;
    {
        double gd[11], s = 0.0;
        for (int i = 0; i < 11; i++) { gd[i] = exp(-((i - 5) * (i - 5)) / 4.5); s += gd[i]; }
        for (int i = 0; i < 11; i++) W.g[i] = (float)(gd[i] / s);
    }

    const int B = 16, C = 3;
    const float scale = 1.0f / (float)(B * C * IMG * IMG);
    const int gy_blocks = (IMG + TH - 1) / TH;              // 11 (last block masked)
    dim3 grid(IMG / TW, gy_blocks, B * C);                  // 16 x 11 x 48 = 8448 blocks
    const int nblocks = (IMG / TW) * gy_blocks * B * C;
    const int use_ws = (ws_size >= (size_t)nblocks * sizeof(float)) ? 1 : 0;

    // d_out is poisoned before every timed launch; both paths accumulate via
    // atomics, so zero it on the stream (memset nodes are graph-capturable).
    hipMemsetAsync(d_out, 0, sizeof(float), stream);
    ssim_tile_kernel<<<grid, 256, 0, stream>>>(x, y, conf, partials, out, use_ws, scale, W);
    if (use_ws) {
        reduce_kernel<<<16, 256, 0, stream>>>(partials, nblocks, out, scale);
    }
}

// Round 4
// 163.123 us; speedup vs baseline: 1.2031x; 1.2031x over previous
//
#include <hip/hip_runtime.h>
#include <cmath>

#define TW 32
#define TH 48
#define HR (TH + 10)     // 58 rows of h-pass results
#define IMG 512
#define SSIM_C1 1e-4f
#define SSIM_C2 9e-4f

struct GaussWin { float g[11]; };

typedef float v2f __attribute__((ext_vector_type(2)));

// VOP3P packed fp32: two FMAs / one instruction. Non-volatile, no memory
// clobber -> compiler may schedule/CSE freely.
__device__ __forceinline__ v2f pk_fma(v2f a, v2f b, v2f c) {
    v2f d;
    asm("v_pk_fma_f32 %0, %1, %2, %3" : "=v"(d) : "v"(a), "v"(b), "v"(c));
    return d;
}
__device__ __forceinline__ v2f pk_mul(v2f a, v2f b) {
    v2f d;
    asm("v_pk_mul_f32 %0, %1, %2" : "=v"(d) : "v"(a), "v"(b));
    return d;
}

// Bank-decorrelating column swizzle (round-3 verified: odd row multiplier).
__device__ __forceinline__ int swz(int col, int row) {
    return (col & 24) | ((col + 2 * (col >> 3) + 5 * row) & 7);
}

__launch_bounds__(256, 4)
__global__ void ssim_tile_kernel(const float* __restrict__ x,
                                 const float* __restrict__ y,
                                 const float* __restrict__ conf,
                                 float* __restrict__ partials,
                                 float* __restrict__ out,
                                 int use_ws, float scale,
                                 GaussWin W) {
    __shared__ float4 s_h4[HR * TW];    // 29696 B  (mu_x, mu_y, sxx, syy)
    __shared__ float  s_h1[HR * TW];    //  7424 B  (sxy)
    __shared__ float  s_red[4];         // total 37 KB -> 4 blocks/CU

    const int tid = threadIdx.x;
    const int plane = blockIdx.z;              // b*3 + c
    const int tx0 = blockIdx.x * TW;
    const int ty0 = blockIdx.y * TH;
    const int pbase = plane * (IMG * IMG);
    const int cbase = (plane / 3) * (IMG * IMG);

    // Gaussian is symmetric: g[k] == g[10-k] bitwise (host computes the same
    // double expression for both). 6 distinct packed weights = 12 VGPRs.
    constexpr int WI[11] = {0,1,2,3,4,5,4,3,2,1,0};
    v2f w2[6];
    #pragma unroll
    for (int i = 0; i < 6; i++) w2[i] = (v2f){W.g[i], W.g[i]};

    // Interior blocks touch no image border anywhere in the halo window:
    // rows need 1<=by<=9, cols need 1<=bx<=14 (see bounds derivation below).
    const bool interior = (blockIdx.x >= 1) & (blockIdx.x <= 14) &
                          (blockIdx.y >= 1) & (blockIdx.y <= 9);

    // ---- Phase 1: horizontal pass, direct from global ----
    // 58 rows x 4 col-groups = 232 strips, one per thread, one round.
    // Strip = 8 output cols; reads 6 aligned float4s per array covering cols
    // [cs-8, cs+16); elements 3..20 are the 18 taps. 16B-aligned reads are
    // fully in- or out-of-bounds -> exact zero padding.
    if (tid < HR * 4) {
        const int r = tid >> 2;
        const int cs = (tid & 3) * 8;
        const int gy = ty0 - 5 + r;
        const float* xrow = x + pbase + gy * IMG;
        const float* yrow = y + pbase + gy * IMG;
        const int c0 = tx0 + cs - 8;

        float4 fx[6], fy[6];
        if (interior) {
            #pragma unroll
            for (int q = 0; q < 6; q++) {
                fx[q] = *(const float4*)(xrow + c0 + 4 * q);
                fy[q] = *(const float4*)(yrow + c0 + 4 * q);
            }
        } else {
            const bool rowok = ((unsigned)gy < IMG);
            #pragma unroll
            for (int q = 0; q < 6; q++) {
                int col = c0 + 4 * q;
                fx[q] = make_float4(0.f, 0.f, 0.f, 0.f);
                fy[q] = make_float4(0.f, 0.f, 0.f, 0.f);
                if (rowok && (unsigned)col <= (unsigned)(IMG - 4)) {
                    fx[q] = *(const float4*)(xrow + col);
                    fy[q] = *(const float4*)(yrow + col);
                }
            }
        }
        float vxa[24], vya[24];
        #pragma unroll
        for (int q = 0; q < 6; q++) {
            vxa[4*q+0]=fx[q].x; vxa[4*q+1]=fx[q].y; vxa[4*q+2]=fx[q].z; vxa[4*q+3]=fx[q].w;
            vya[4*q+0]=fy[q].x; vya[4*q+1]=fy[q].y; vya[4*q+2]=fy[q].z; vya[4*q+3]=fy[q].w;
        }

        // Streaming tap-major conv: keeps live set ~50 VGPR (accs + 1 tap).
        v2f amu[8], as2[8];
        float axy[8];
        #pragma unroll
        for (int j = 0; j < 8; j++) { amu[j]=(v2f){0.f,0.f}; as2[j]=(v2f){0.f,0.f}; axy[j]=0.f; }
        #pragma unroll
        for (int k = 0; k < 18; k++) {
            float xv = vxa[k + 3], yv = vya[k + 3];
            v2f xy = (v2f){xv, yv};
            v2f p2 = pk_mul(xy, xy);          // (x^2, y^2)
            float pxy = xv * yv;
            const int jlo = (k - 10 > 0) ? (k - 10) : 0;
            const int jhi = (k < 7) ? k : 7;
            #pragma unroll
            for (int j = jlo; j <= jhi; j++) {
                v2f w = w2[WI[k - j]];
                amu[j] = pk_fma(xy, w, amu[j]);
                as2[j] = pk_fma(p2, w, as2[j]);
                axy[j] = fmaf(pxy, w.x, axy[j]);
            }
        }
        const int quad = cs & 24;
        const int base0 = cs + 2 * (cs >> 3) + 5 * r;
        #pragma unroll
        for (int j = 0; j < 8; j++) {
            int pc = quad | ((base0 + j) & 7);
            s_h4[r * TW + pc] = make_float4(amu[j].x, amu[j].y, as2[j].x, as2[j].y);
            s_h1[r * TW + pc] = axy[j];
        }
    }

    // Prefetch conf (consumed in epilogue) before the barrier.
    const int c  = tid & 31;
    const int r0 = (tid >> 5) * 6;            // 8 groups x 6 rows = 48 rows
    float cf[6];
    #pragma unroll
    for (int j = 0; j < 6; j++) {
        int gy = ty0 + r0 + j;
        cf[j] = (gy < IMG) ? conf[cbase + gy * IMG + tx0 + c] : 0.f;
    }
    __syncthreads();

    // ---- Phase 2: vertical pass, 6 vertically-adjacent outputs per thread ----
    v2f amu[6], as2[6];
    float axy[6];
    #pragma unroll
    for (int j = 0; j < 6; j++) { amu[j]=(v2f){0.f,0.f}; as2[j]=(v2f){0.f,0.f}; axy[j]=0.f; }

    const int cquad = c & 24;
    const int cb0 = c + 2 * (c >> 3);
    #pragma unroll
    for (int t = 0; t < 16; t++) {
        int row = r0 + t;
        int pc = cquad | ((cb0 + 5 * row) & 7);
        float4 h4 = s_h4[row * TW + pc];
        float  h1 = s_h1[row * TW + pc];
        v2f hmu = (v2f){h4.x, h4.y};
        v2f hs2 = (v2f){h4.z, h4.w};
        #pragma unroll
        for (int j = 0; j < 6; j++) {
            int k = t - j;                    // constant post-unroll
            if (k >= 0 && k <= 10) {
                v2f w = w2[WI[k]];
                amu[j] = pk_fma(hmu, w, amu[j]);
                as2[j] = pk_fma(hs2, w, as2[j]);
                axy[j] = fmaf(h1, w.x, axy[j]);
            }
        }
    }

    // ---- Epilogue: SSIM + conf weighting + accumulate ----
    // Out-of-image rows (by==10 tail) have cf==0 and finite loss (den>=C1*C2>0),
    // so fmaf(loss, 0, s) contributes exactly 0 -- no branch needed.
    float lsum = 0.f;
    #pragma unroll
    for (int j = 0; j < 6; j++) {
        float mu_x = amu[j].x, mu_y = amu[j].y;
        float mu_x2 = mu_x * mu_x;
        float mu_y2 = mu_y * mu_y;
        float mu_xy = mu_x * mu_y;
        float sigx  = as2[j].x - mu_x2;
        float sigy  = as2[j].y - mu_y2;
        float sigxy = axy[j] - mu_xy;
        float num = (2.f * mu_xy + SSIM_C1) * (2.f * sigxy + SSIM_C2);
        float den = (mu_x2 + mu_y2 + SSIM_C1) * (sigx + sigy + SSIM_C2);
        float ssim = num * __builtin_amdgcn_rcpf(den);   // den >= C1*C2 > 0
        float loss = 1.f - ssim;
        loss = fminf(fmaxf(loss, 0.f), 1.f);
        lsum = fmaf(loss, cf[j], lsum);
    }

    // ---- Block reduction ----
    #pragma unroll
    for (int off = 32; off; off >>= 1) lsum += __shfl_down(lsum, off, 64);
    if ((tid & 63) == 0) s_red[tid >> 6] = lsum;
    __syncthreads();
    if (tid == 0) {
        float t = s_red[0] + s_red[1] + s_red[2] + s_red[3];
        if (use_ws) {
            partials[blockIdx.x + gridDim.x * (blockIdx.y + gridDim.y * blockIdx.z)] = t;
        } else {
            atomicAdd(out, t * scale);
        }
    }
}

// Single-block reduce: writes out[0] directly (no memset, no atomics).
__global__ void reduce_kernel(const float* __restrict__ partials, int n,
                              float* __restrict__ out, float scale) {
    __shared__ float s_red[16];
    float s = 0.f;
    const float4* p4 = (const float4*)partials;
    const int n4 = n >> 2;
    for (int i = threadIdx.x; i < n4; i += 1024) {
        float4 v = p4[i];
        s += (v.x + v.y) + (v.z + v.w);
    }
    for (int i = (n4 << 2) + threadIdx.x; i < n; i += 1024) s += partials[i];
    #pragma unroll
    for (int off = 32; off; off >>= 1) s += __shfl_down(s, off, 64);
    if ((threadIdx.x & 63) == 0) s_red[threadIdx.x >> 6] = s;
    __syncthreads();
    if (threadIdx.x == 0) {
        float t = 0.f;
        #pragma unroll
        for (int i = 0; i < 16; i++) t += s_red[i];
        out[0] = t * scale;
    }
}

extern "C" void kernel_launch(void* const* d_in, const int* in_sizes, int n_in,
                              void* d_out, int out_size, void* d_ws, size_t ws_size,
                              hipStream_t stream) {
    const float* x    = (const float*)d_in[0];
    const float* y    = (const float*)d_in[1];
    const float* conf = (const float*)d_in[2];
    float* out = (float*)d_out;
    float* partials = (float*)d_ws;

    // Gaussian window, computed like the reference: float64 exp + normalize, cast f32
    GaussWin W;
    {
        double gd[11], s = 0.0;
        for (int i = 0; i < 11; i++) { gd[i] = exp(-((i - 5) * (i - 5)) / 4.5); s += gd[i]; }
        for (int i = 0; i < 11; i++) W.g[i] = (float)(gd[i] / s);
    }

    const int B = 16, C = 3;
    const float scale = 1.0f / (float)(B * C * IMG * IMG);
    const int gy_blocks = (IMG + TH - 1) / TH;              // 11 (last block masked)
    dim3 grid(IMG / TW, gy_blocks, B * C);                  // 16 x 11 x 48 = 8448 blocks
    const int nblocks = (IMG / TW) * gy_blocks * B * C;
    const int use_ws = (ws_size >= (size_t)nblocks * sizeof(float)) ? 1 : 0;

    if (!use_ws) {
        // fallback: atomic accumulation into d_out (poisoned before each call)
        hipMemsetAsync(d_out, 0, sizeof(float), stream);
    }
    ssim_tile_kernel<<<grid, 256, 0, stream>>>(x, y, conf, partials, out, use_ws, scale, W);
    if (use_ws) {
        reduce_kernel<<<1, 1024, 0, stream>>>(partials, nblocks, out, scale);
    }
}

// Round 5
// 160.508 us; speedup vs baseline: 1.2227x; 1.0163x over previous
//
#include <hip/hip_runtime.h>
#include <cmath>

#define TW 32
#define TH 48
#define HR (TH + 10)     // 58 rows of h-pass results
#define IMG 512
#define SSIM_C1 1e-4f
#define SSIM_C2 9e-4f

struct GaussWin { float g[11]; };

typedef float v2f __attribute__((ext_vector_type(2)));

// Native packed fp32: clang/LLVM select v_pk_fma_f32 / v_pk_mul_f32 for
// <2 x float> on gfx90a+ (HasPackedFP32Ops). Unlike the round-4 inline asm,
// the compiler can coalesce the accumulator (no v_mov per FMA) and schedule
// freely.
__device__ __forceinline__ v2f pk_fma(v2f a, v2f b, v2f c) {
    return __builtin_elementwise_fma(a, b, c);
}
__device__ __forceinline__ v2f pk_mul(v2f a, v2f b) { return a * b; }

__launch_bounds__(256, 4)
__global__ void ssim_tile_kernel(const float* __restrict__ x,
                                 const float* __restrict__ y,
                                 const float* __restrict__ conf,
                                 float* __restrict__ partials,
                                 float* __restrict__ out,
                                 int use_ws, float scale,
                                 GaussWin W) {
    __shared__ float4 s_h4[HR * TW];    // 29696 B  (mu_x, mu_y, sxx, syy)
    __shared__ float  s_h1[HR * TW];    //  7424 B  (sxy)
    __shared__ float  s_red[4];         // total 37 KB -> 4 blocks/CU

    const int tid = threadIdx.x;
    const int plane = blockIdx.z;              // b*3 + c
    const int tx0 = blockIdx.x * TW;
    const int ty0 = blockIdx.y * TH;
    const int pbase = plane * (IMG * IMG);
    const int cbase = (plane / 3) * (IMG * IMG);

    // Gaussian symmetric: g[k] == g[10-k] bitwise. 6 distinct packed weights.
    constexpr int WI[11] = {0,1,2,3,4,5,4,3,2,1,0};
    v2f w2[6];
    #pragma unroll
    for (int i = 0; i < 6; i++) w2[i] = (v2f){W.g[i], W.g[i]};

    // Interior blocks touch no image border anywhere in the halo window.
    const bool interior = (blockIdx.x >= 1) & (blockIdx.x <= 14) &
                          (blockIdx.y >= 1) & (blockIdx.y <= 9);

    // ---- Phase 1: horizontal pass, direct from global ----
    // 58 rows x 4 col-groups = 232 strips, one per thread, one round.
    // Strip = 8 output cols; reads 6 aligned float4s per array covering cols
    // [cs-8, cs+16); elements 3..20 are the 18 taps. 16B-aligned reads are
    // fully in- or out-of-bounds -> exact zero padding.
    if (tid < HR * 4) {
        const int r = tid >> 2;
        const int cs = (tid & 3) * 8;
        const int gy = ty0 - 5 + r;
        const float* xrow = x + pbase + gy * IMG;
        const float* yrow = y + pbase + gy * IMG;
        const int c0 = tx0 + cs - 8;

        float4 fx[6], fy[6];
        if (interior) {
            #pragma unroll
            for (int q = 0; q < 6; q++) {
                fx[q] = *(const float4*)(xrow + c0 + 4 * q);
                fy[q] = *(const float4*)(yrow + c0 + 4 * q);
            }
        } else {
            const bool rowok = ((unsigned)gy < IMG);
            #pragma unroll
            for (int q = 0; q < 6; q++) {
                int col = c0 + 4 * q;
                fx[q] = make_float4(0.f, 0.f, 0.f, 0.f);
                fy[q] = make_float4(0.f, 0.f, 0.f, 0.f);
                if (rowok && (unsigned)col <= (unsigned)(IMG - 4)) {
                    fx[q] = *(const float4*)(xrow + col);
                    fy[q] = *(const float4*)(yrow + col);
                }
            }
        }
        float vxa[24], vya[24];
        #pragma unroll
        for (int q = 0; q < 6; q++) {
            vxa[4*q+0]=fx[q].x; vxa[4*q+1]=fx[q].y; vxa[4*q+2]=fx[q].z; vxa[4*q+3]=fx[q].w;
            vya[4*q+0]=fy[q].x; vya[4*q+1]=fy[q].y; vya[4*q+2]=fy[q].z; vya[4*q+3]=fy[q].w;
        }

        // Streaming tap-major conv.
        v2f amu[8], as2[8];
        float axy[8];
        #pragma unroll
        for (int j = 0; j < 8; j++) { amu[j]=(v2f){0.f,0.f}; as2[j]=(v2f){0.f,0.f}; axy[j]=0.f; }
        #pragma unroll
        for (int k = 0; k < 18; k++) {
            float xv = vxa[k + 3], yv = vya[k + 3];
            v2f xy = (v2f){xv, yv};
            v2f p2 = pk_mul(xy, xy);          // (x^2, y^2)
            float pxy = xv * yv;
            const int jlo = (k - 10 > 0) ? (k - 10) : 0;
            const int jhi = (k < 7) ? k : 7;
            #pragma unroll
            for (int j = jlo; j <= jhi; j++) {
                v2f w = w2[WI[k - j]];
                amu[j] = pk_fma(xy, w, amu[j]);
                as2[j] = pk_fma(p2, w, as2[j]);
                axy[j] = fmaf(pxy, w.x, axy[j]);
            }
        }
        const int quad = cs & 24;
        const int base0 = cs + 2 * (cs >> 3) + 5 * r;
        #pragma unroll
        for (int j = 0; j < 8; j++) {
            int pc = quad | ((base0 + j) & 7);
            s_h4[r * TW + pc] = make_float4(amu[j].x, amu[j].y, as2[j].x, as2[j].y);
            s_h1[r * TW + pc] = axy[j];
        }
    }

    // Prefetch conf (consumed in epilogue) before the barrier.
    const int c  = tid & 31;
    const int r0 = (tid >> 5) * 6;            // 8 groups x 6 rows = 48 rows
    float cf[6];
    #pragma unroll
    for (int j = 0; j < 6; j++) {
        int gy = ty0 + r0 + j;
        cf[j] = (gy < IMG) ? conf[cbase + gy * IMG + tx0 + c] : 0.f;
    }
    __syncthreads();

    // ---- Phase 2: vertical pass, 6 vertically-adjacent outputs per thread ----
    v2f amu[6], as2[6];
    float axy[6];
    #pragma unroll
    for (int j = 0; j < 6; j++) { amu[j]=(v2f){0.f,0.f}; as2[j]=(v2f){0.f,0.f}; axy[j]=0.f; }

    const int cquad = c & 24;
    const int cb0 = c + 2 * (c >> 3) + 5 * r0;
    #pragma unroll
    for (int t = 0; t < 16; t++) {
        int row = r0 + t;
        int pc = cquad | ((cb0 + 5 * t) & 7);
        float4 h4 = s_h4[row * TW + pc];
        float  h1 = s_h1[row * TW + pc];
        v2f hmu = (v2f){h4.x, h4.y};
        v2f hs2 = (v2f){h4.z, h4.w};
        #pragma unroll
        for (int j = 0; j < 6; j++) {
            int k = t - j;                    // constant post-unroll
            if (k >= 0 && k <= 10) {
                v2f w = w2[WI[k]];
                amu[j] = pk_fma(hmu, w, amu[j]);
                as2[j] = pk_fma(hs2, w, as2[j]);
                axy[j] = fmaf(h1, w.x, axy[j]);
            }
        }
    }

    // ---- Epilogue: SSIM + conf weighting + accumulate ----
    // Out-of-image rows (by==10 tail) have cf==0 and finite loss (den>0),
    // so they contribute exactly 0 -- no branch needed.
    float lsum = 0.f;
    #pragma unroll
    for (int j = 0; j < 6; j++) {
        float mu_x = amu[j].x, mu_y = amu[j].y;
        float mu_x2 = mu_x * mu_x;
        float mu_y2 = mu_y * mu_y;
        float mu_xy = mu_x * mu_y;
        float sigx  = as2[j].x - mu_x2;
        float sigy  = as2[j].y - mu_y2;
        float sigxy = axy[j] - mu_xy;
        float num = (2.f * mu_xy + SSIM_C1) * (2.f * sigxy + SSIM_C2);
        float den = (mu_x2 + mu_y2 + SSIM_C1) * (sigx + sigy + SSIM_C2);
        float ssim = num * __builtin_amdgcn_rcpf(den);   // den >= C1*C2 > 0
        float loss = 1.f - ssim;
        loss = fminf(fmaxf(loss, 0.f), 1.f);
        lsum = fmaf(loss, cf[j], lsum);
    }

    // ---- Block reduction ----
    #pragma unroll
    for (int off = 32; off; off >>= 1) lsum += __shfl_down(lsum, off, 64);
    if ((tid & 63) == 0) s_red[tid >> 6] = lsum;
    __syncthreads();
    if (tid == 0) {
        float t = s_red[0] + s_red[1] + s_red[2] + s_red[3];
        if (use_ws) {
            partials[blockIdx.x + gridDim.x * (blockIdx.y + gridDim.y * blockIdx.z)] = t;
        } else {
            atomicAdd(out, t * scale);
        }
    }
}

// Single-block reduce: writes out[0] directly (no memset, no atomics).
__global__ void reduce_kernel(const float* __restrict__ partials, int n,
                              float* __restrict__ out, float scale) {
    __shared__ float s_red[16];
    float s = 0.f;
    const float4* p4 = (const float4*)partials;
    const int n4 = n >> 2;
    for (int i = threadIdx.x; i < n4; i += 1024) {
        float4 v = p4[i];
        s += (v.x + v.y) + (v.z + v.w);
    }
    for (int i = (n4 << 2) + threadIdx.x; i < n; i += 1024) s += partials[i];
    #pragma unroll
    for (int off = 32; off; off >>= 1) s += __shfl_down(s, off, 64);
    if ((threadIdx.x & 63) == 0) s_red[threadIdx.x >> 6] = s;
    __syncthreads();
    if (threadIdx.x == 0) {
        float t = 0.f;
        #pragma unroll
        for (int i = 0; i < 16; i++) t += s_red[i];
        out[0] = t * scale;
    }
}

extern "C" void kernel_launch(void* const* d_in, const int* in_sizes, int n_in,
                              void* d_out, int out_size, void* d_ws, size_t ws_size,
                              hipStream_t stream) {
    const float* x    = (const float*)d_in[0];
    const float* y    = (const float*)d_in[1];
    const float* conf = (const float*)d_in[2];
    float* out = (float*)d_out;
    float* partials = (float*)d_ws;

    // Gaussian window, computed like the reference: float64 exp + normalize, cast f32
    GaussWin W;
    {
        double gd[11], s = 0.0;
        for (int i = 0; i < 11; i++) { gd[i] = exp(-((i - 5) * (i - 5)) / 4.5); s += gd[i]; }
        for (int i = 0; i < 11; i++) W.g[i] = (float)(gd[i] / s);
    }

    const int B = 16, C = 3;
    const float scale = 1.0f / (float)(B * C * IMG * IMG);
    const int gy_blocks = (IMG + TH - 1) / TH;              // 11 (last block masked)
    dim3 grid(IMG / TW, gy_blocks, B * C);                  // 16 x 11 x 48 = 8448 blocks
    const int nblocks = (IMG / TW) * gy_blocks * B * C;
    const int use_ws = (ws_size >= (size_t)nblocks * sizeof(float)) ? 1 : 0;

    if (!use_ws) {
        // fallback: atomic accumulation into d_out (poisoned before each call)
        hipMemsetAsync(d_out, 0, sizeof(float), stream);
    }
    ssim_tile_kernel<<<grid, 256, 0, stream>>>(x, y, conf, partials, out, use_ws, scale, W);
    if (use_ws) {
        reduce_kernel<<<1, 1024, 0, stream>>>(partials, nblocks, out, scale);
    }
}